// Round 1
// baseline (249.130 us; speedup 1.0000x reference)
//
#include <hip/hip_runtime.h>

#define B_ 8
#define S_ 2048
#define IN_ 4096
#define OUT_ 4096
#define R_ 16
#define E_ 64

__device__ __forceinline__ float dot4(float4 a, float4 b) {
  return a.x*b.x + a.y*b.y + a.z*b.z + a.w*b.w;
}

// ---------------- K1a: score dots -------------------------------------------
// grid 64 = (b=8) x (eg=8); each block: 8 experts, one expert-pair per wave.
// scoresA[b][e] = q_b . W_rA[e] + b_rA[e];  gB0[b][e] = q_b . W_rB[e] + b_rB[e]
__global__ __launch_bounds__(256) void k_scores(
    const float* __restrict__ q, const float* __restrict__ W_rA,
    const float* __restrict__ b_rA, const float* __restrict__ W_rB,
    const float* __restrict__ b_rB, float* __restrict__ scoresA,
    float* __restrict__ gB0)
{
  const int b = blockIdx.x >> 3, eg = blockIdx.x & 7;
  __shared__ float qs[IN_];
  const int tid = threadIdx.x;
  {
    const float4* q4 = (const float4*)(q + (size_t)b * IN_);
    float4* qs4 = (float4*)qs;
    for (int i = tid; i < IN_ / 4; i += 256) qs4[i] = q4[i];
  }
  __syncthreads();
  const int wave = tid >> 6, lane = tid & 63;
  const float4* qs4 = (const float4*)qs;
  for (int k = 0; k < 2; ++k) {
    const int e = eg * 8 + wave * 2 + k;
    const float4* wa = (const float4*)(W_rA + (size_t)e * IN_);
    const float4* wb = (const float4*)(W_rB + (size_t)e * IN_);
    float pa = 0.f, pb = 0.f;
    for (int i = lane; i < IN_ / 4; i += 64) {
      float4 qv = qs4[i];
      pa += dot4(qv, wa[i]);
      pb += dot4(qv, wb[i]);
    }
    #pragma unroll
    for (int off = 1; off < 64; off <<= 1) {
      pa += __shfl_xor(pa, off, 64);
      pb += __shfl_xor(pb, off, 64);
    }
    if (lane == 0) {
      scoresA[b * E_ + e] = pa + b_rA[e];
      gB0[b * E_ + e]     = pb + b_rB[e];
    }
  }
}

// wave-parallel top-16 (descending, ties -> lower index, matching lax.top_k)
__device__ __forceinline__ void topk16(float v, int* __restrict__ dst) {
  const int lane = threadIdx.x & 63;
  for (int r = 0; r < R_; ++r) {
    float mv = v; int mi = lane;
    #pragma unroll
    for (int off = 1; off < 64; off <<= 1) {
      float v2 = __shfl_xor(mv, off, 64);
      int   i2 = __shfl_xor(mi, off, 64);
      if (v2 > mv || (v2 == mv && i2 < mi)) { mv = v2; mi = i2; }
    }
    if (lane == 0) dst[r] = mi;
    if (lane == mi) v = -__builtin_inff();
  }
}

__global__ __launch_bounds__(64) void k_topk_a(
    const float* __restrict__ scoresA, int* __restrict__ idxA)
{
  const int b = blockIdx.x;
  topk16(scoresA[b * E_ + (threadIdx.x & 63)], idxA + b * R_);
}

// ---------------- K1b: cfs einsum partials -----------------------------------
// grid 64 = (r=16) x (ic=4, chunks of 1024 over IN).  Reads cfs_W exactly once.
// gBpart[blk][b][e] = sum_{i in chunk} A_pool[idxA[b][r], r, i] * cfs_W[r, i, e]
__global__ __launch_bounds__(256) void k_cfs(
    const float* __restrict__ A_pool, const float* __restrict__ cfs,
    const int* __restrict__ idxA, float* __restrict__ gBpart)
{
  const int blk = blockIdx.x;
  const int r = blk >> 2, ic = blk & 3;
  __shared__ float as[B_][1024];
  __shared__ float red[4][B_][E_];
  const int tid = threadIdx.x;
  {
    const int b = tid >> 5, t = tid & 31;  // 32 threads per batch row
    const int e = idxA[b * R_ + r];
    const float4* src = (const float4*)(A_pool + ((size_t)e * R_ + r) * IN_ + ic * 1024);
    float4* dst = (float4*)as[b];
    for (int j = t; j < 256; j += 32) dst[j] = src[j];
  }
  __syncthreads();
  const int e = tid & 63, part = tid >> 6;
  float acc[B_];
  #pragma unroll
  for (int b = 0; b < B_; ++b) acc[b] = 0.f;
  const float* cbase = cfs + ((size_t)r * IN_ + ic * 1024) * E_ + e;
  for (int i = part * 256; i < part * 256 + 256; ++i) {
    float c = cbase[(size_t)i * E_];
    #pragma unroll
    for (int b = 0; b < B_; ++b) acc[b] += as[b][i] * c;
  }
  #pragma unroll
  for (int b = 0; b < B_; ++b) red[part][b][e] = acc[b];
  __syncthreads();
  if (tid < 64) {
    #pragma unroll
    for (int b = 0; b < B_; ++b) {
      float s = red[0][b][tid] + red[1][b][tid] + red[2][b][tid] + red[3][b][tid];
      gBpart[((size_t)blk * B_ + b) * E_ + tid] = s;
    }
  }
}

__global__ __launch_bounds__(64) void k_topk_b(
    const float* __restrict__ gB0, const float* __restrict__ gBpart,
    int* __restrict__ idxB)
{
  const int b = blockIdx.x;
  const int lane = threadIdx.x & 63;
  float v = gB0[b * E_ + lane];
  for (int blk = 0; blk < 64; ++blk)
    v += gBpart[((size_t)blk * B_ + b) * E_ + lane];
  topk16(v, idxB + b * R_);
}

// ---------------- K2: pack lora_B --------------------------------------------
// lora_Bp[b][r][o] = B_pool[idxB[b][r], o, r]   (strided gather -> coalesced layout)
__global__ __launch_bounds__(256) void k_pack_b(
    const float* __restrict__ B_pool, const int* __restrict__ idxB,
    float* __restrict__ loraBp)
{
  const int blk = blockIdx.x;            // 128 = b*16 + r
  const int b = blk >> 4, r = blk & 15;
  const int e = idxB[b * R_ + r];
  const float* src = B_pool + (size_t)e * OUT_ * R_ + r;
  float* dst = loraBp + (size_t)(b * R_ + r) * OUT_;
  for (int o = threadIdx.x; o < OUT_; o += 256) dst[o] = src[(size_t)o * R_];
}

// ---------------- K3: after_A = x @ lora_A^T (split-K) -----------------------
// grid 512 = (rowblock=64) x (ks=8).  Each block: 256 rows x 16 r, K-chunk 512.
// Thread: 4 rows x 16 r accumulators, 4-lane i-split (p) for 64B-coalesced x.
__global__ __launch_bounds__(256) void k_after(
    const float* __restrict__ x, const float* __restrict__ A_pool,
    const int* __restrict__ idxA, float* __restrict__ partial)
{
  const int bx = blockIdx.x;
  const int rb = bx & 63, ks = bx >> 6;
  const int b = rb >> 3;
  const int srow0 = (rb & 7) * 256;
  __shared__ float4 as4[R_][128];  // [16][512 floats] = 32 KB
  const int tid = threadIdx.x;
  {
    const int r = tid >> 4, t = tid & 15;  // 16 threads per rank row
    const int e = idxA[b * R_ + r];
    const float4* src = (const float4*)(A_pool + ((size_t)e * R_ + r) * IN_ + ks * 512);
    for (int j = t; j < 128; j += 16) as4[r][j] = src[j];
  }
  __syncthreads();
  const int rg = tid >> 2, p = tid & 3;
  const int row0 = srow0 + rg * 4;
  const float* xbase = x + ((size_t)b * S_ + row0) * IN_ + ks * 512;
  float acc[4][R_];
  #pragma unroll
  for (int m = 0; m < 4; ++m)
    #pragma unroll
    for (int r = 0; r < R_; ++r) acc[m][r] = 0.f;

  for (int step = 0; step < 32; ++step) {
    const int i4 = step * 4 + p;  // float4 index within 512-float chunk
    float4 xv[4];
    #pragma unroll
    for (int m = 0; m < 4; ++m)
      xv[m] = *(const float4*)(xbase + (size_t)m * IN_ + i4 * 4);
    #pragma unroll
    for (int r = 0; r < R_; ++r) {
      float4 a = as4[r][i4];
      #pragma unroll
      for (int m = 0; m < 4; ++m) {
        acc[m][r] += xv[m].x * a.x + xv[m].y * a.y + xv[m].z * a.z + xv[m].w * a.w;
      }
    }
  }
  // reduce across the 4 p-lanes
  #pragma unroll
  for (int m = 0; m < 4; ++m)
    #pragma unroll
    for (int r = 0; r < R_; ++r) {
      float v = acc[m][r];
      v += __shfl_xor(v, 1, 64);
      v += __shfl_xor(v, 2, 64);
      acc[m][r] = v;
    }
  if (p == 0) {
    float* dst = partial + (((size_t)ks * B_ + b) * S_ + row0) * R_;
    #pragma unroll
    for (int m = 0; m < 4; ++m) {
      float4* d4 = (float4*)(dst + (size_t)m * R_);
      d4[0] = make_float4(acc[m][0],  acc[m][1],  acc[m][2],  acc[m][3]);
      d4[1] = make_float4(acc[m][4],  acc[m][5],  acc[m][6],  acc[m][7]);
      d4[2] = make_float4(acc[m][8],  acc[m][9],  acc[m][10], acc[m][11]);
      d4[3] = make_float4(acc[m][12], acc[m][13], acc[m][14], acc[m][15]);
    }
  }
}

// ---------------- K3b: sum split-K partials ----------------------------------
__global__ __launch_bounds__(256) void k_reduce(
    const float* __restrict__ partial, float* __restrict__ afterA)
{
  const int idx = blockIdx.x * 256 + threadIdx.x;  // 65536 float4s
  const float4* p4 = (const float4*)partial;
  const int stride = B_ * S_ * R_ / 4;
  float4 s = p4[idx];
  #pragma unroll
  for (int k = 1; k < 8; ++k) {
    float4 t = p4[(size_t)k * stride + idx];
    s.x += t.x; s.y += t.y; s.z += t.z; s.w += t.w;
  }
  ((float4*)afterA)[idx] = s;
}

// ---------------- K4: out = after_A @ lora_Bp --------------------------------
// grid 512 = b(8) x oc(4) x st(16).  B-fragments in registers, coalesced stores.
__global__ __launch_bounds__(256) void k_out(
    const float* __restrict__ afterA, const float* __restrict__ loraBp,
    float* __restrict__ out)
{
  const int bx = blockIdx.x;
  const int b = bx >> 6, oc = (bx >> 4) & 3, st = bx & 15;
  __shared__ float aa[128 * R_];  // 8 KB
  const int tid = threadIdx.x;
  {
    const float4* src = (const float4*)(afterA + ((size_t)b * S_ + st * 128) * R_);
    float4* aa4 = (float4*)aa;
    for (int j = tid; j < 512; j += 256) aa4[j] = src[j];
  }
  float4 Bf[R_];
  #pragma unroll
  for (int r = 0; r < R_; ++r)
    Bf[r] = *(const float4*)(loraBp + (size_t)(b * R_ + r) * OUT_ + oc * 1024 + tid * 4);
  __syncthreads();
  float* obase = out + ((size_t)b * S_ + st * 128) * OUT_ + oc * 1024 + tid * 4;
  for (int s = 0; s < 128; ++s) {
    const float* a = aa + s * R_;
    float4 acc = make_float4(0.f, 0.f, 0.f, 0.f);
    #pragma unroll
    for (int r = 0; r < R_; ++r) {
      float av = a[r];
      acc.x += av * Bf[r].x; acc.y += av * Bf[r].y;
      acc.z += av * Bf[r].z; acc.w += av * Bf[r].w;
    }
    *(float4*)(obase + (size_t)s * OUT_) = acc;
  }
}

// ---------------- launch ------------------------------------------------------
extern "C" void kernel_launch(void* const* d_in, const int* in_sizes, int n_in,
                              void* d_out, int out_size, void* d_ws, size_t ws_size,
                              hipStream_t stream) {
  const float* x      = (const float*)d_in[0];
  const float* qsig   = (const float*)d_in[1];
  const float* A_pool = (const float*)d_in[2];
  const float* B_pool = (const float*)d_in[3];
  const float* W_rA   = (const float*)d_in[4];
  const float* b_rA   = (const float*)d_in[5];
  const float* W_rB   = (const float*)d_in[6];
  const float* b_rB   = (const float*)d_in[7];
  const float* cfs_W  = (const float*)d_in[8];
  float* out = (float*)d_out;

  char* w = (char*)d_ws;
  int*   idxA    = (int*)(w);                      // 512 B
  int*   idxB    = (int*)(w + 512);                // 512 B
  float* scoresA = (float*)(w + 1024);             // 2 KB
  float* gB0     = (float*)(w + 3072);             // 2 KB
  float* gBpart  = (float*)(w + 5120);             // 64*8*64*4 = 128 KB
  float* loraBp  = (float*)(w + 136192);           // 8*16*4096*4 = 2 MB
  float* partial = (float*)(w + 2233344);          // 8*8*2048*16*4 = 16 MB
  float* afterA  = (float*)(w + 19010560);         // 2 MB (ends ~21.1 MB)

  k_scores<<<64, 256, 0, stream>>>(qsig, W_rA, b_rA, W_rB, b_rB, scoresA, gB0);
  k_topk_a<<<8, 64, 0, stream>>>(scoresA, idxA);
  k_cfs<<<64, 256, 0, stream>>>(A_pool, cfs_W, idxA, gBpart);
  k_topk_b<<<8, 64, 0, stream>>>(gB0, gBpart, idxB);
  k_pack_b<<<128, 256, 0, stream>>>(B_pool, idxB, loraBp);
  k_after<<<512, 256, 0, stream>>>(x, A_pool, idxA, partial);
  k_reduce<<<256, 256, 0, stream>>>(partial, afterA);
  k_out<<<512, 256, 0, stream>>>(afterA, loraBp, out);
}